// Round 9
// baseline (387.594 us; speedup 1.0000x reference)
//
#include <hip/hip_runtime.h>
#include <stdint.h>

// VectorQuantizer (eval fwd): inputs [64,64,32,32] f32 NCHW, embedding [1024,64] f32.
// Outputs concatenated: quantized [64,64,32,32] f32, loss scalar, perplexity scalar.
//
// Round-9: round-8 fused structure, scaled for TLP + lower lgkm mixing.
//  - 512-thread blocks: 8 waves, k-split 8 x 128 codes, 64 rows/block.
//    grid 1024 -> 4 blocks/CU -> 8 waves/SIMD (was 4): feed stalls overlap.
//  - code-group 16 (acc[16]): one x ds_read pair per 1024 FMA-cycles (was
//    per 512) -> the shared lgkmcnt (ds_read + s_load) drains half as often.
//  - e/e2 via readfirstlane-uniform addresses -> s_load scalar pipe (r8-proven).
// Distance arithmetic unchanged: dist = ||e||^2 - 2 x.e (bit-exact selections,
// absmax 0.0 in rounds 2/3/5/6/7/8).

#define K_CODES 1024
#define DIM 64
#define HW 1024          // 32*32
#define N_ROWS 65536
#define OUT_ELEMS 4194304
#define XSTR 68          // x row stride in dwords

// ws layout (float indices)
#define WS_E2   0        // 1024 f32: ||e_k||^2
#define WS_CNT  1024     // 1024 u32: counts
#define WS_LOSS 2048     // 1 f32

__global__ void vq_init(const float* __restrict__ emb, float* __restrict__ ws) {
    const int k = blockIdx.x * blockDim.x + threadIdx.x;  // 1024 threads total
    if (k < K_CODES) {
        const float4* e4 = reinterpret_cast<const float4*>(emb + k * DIM);
        float s = 0.f;
#pragma unroll
        for (int i = 0; i < DIM / 4; ++i) {
            float4 v = e4[i];
            s += v.x * v.x + v.y * v.y + v.z * v.z + v.w * v.w;
        }
        ws[WS_E2 + k] = s;
        reinterpret_cast<unsigned int*>(ws)[WS_CNT + k] = 0u;
    }
    if (blockIdx.x == 0 && threadIdx.x == 0) ws[WS_LOSS] = 0.f;
}

__global__ __launch_bounds__(512, 8) void vq_main(
    const float* __restrict__ in, const float* __restrict__ emb,
    float* __restrict__ out, float* __restrict__ ws)
{
    __shared__ __align__(16) float xs[64 * XSTR];   // 17408 B
    __shared__ float bwd[8][64];
    __shared__ int   bwk[8][64];
    __shared__ int   fk[64];
    __shared__ float lred[8];

    const int t = threadIdx.x;
    const int w = t >> 6;        // wave id 0..7
    const int l = t & 63;        // pixel-row within block
    const int w_u = __builtin_amdgcn_readfirstlane(w);   // SGPR wave id

    const int row0 = blockIdx.x * 64;
    const int b = row0 >> 10, hw0 = row0 & 1023;
    const float* xin = in + b * (DIM * HW) + hw0;

    // ---- stage x tile: thread (w,l) loads channels [8w, 8w+8) of row l ----
#pragma unroll
    for (int cc = 0; cc < 8; ++cc) {
        const int c = w * 8 + cc;
        xs[l * XSTR + c] = xin[c * HW + l];   // lanes l consecutive -> coalesced
    }
    __syncthreads();

    // ---- argmin over this wave's 128 codes (k0 wave-uniform) ----
    const float* e2 = ws + WS_E2;
    const float* xrow = xs + l * XSTR;
    float best = 3.4e38f;
    int   bestk = 0;
    const int k0 = w_u * 128;

    for (int kg = 0; kg < 128; kg += 16) {
        float acc[16];
#pragma unroll
        for (int c = 0; c < 16; ++c) acc[c] = 0.f;
#pragma unroll
        for (int ch = 0; ch < 8; ++ch) {
            float xc[8];
            *(float4*)(xc)     = *(const float4*)(xrow + ch * 8);      // ds_read_b128
            *(float4*)(xc + 4) = *(const float4*)(xrow + ch * 8 + 4);  // ds_read_b128
#pragma unroll
            for (int c = 0; c < 16; ++c) {
                const float* e = emb + (k0 + kg + c) * DIM + ch * 8;   // uniform -> s_load
#pragma unroll
                for (int j = 0; j < 8; ++j)
                    acc[c] = fmaf(e[j], xc[j], acc[c]);
            }
        }
#pragma unroll
        for (int c = 0; c < 16; ++c) {
            const int k = k0 + kg + c;
            const float dist = fmaf(-2.f, acc[c], e2[k]);
            if (dist < best) { best = dist; bestk = k; }   // strict < : first occurrence
        }
    }

    bwd[w][l] = best;
    bwk[w][l] = bestk;
    __syncthreads();

    // ---- lex-merge across the 8 waves (k-ranges ascending) ----
    if (t < 64) {
        float bb = bwd[0][t]; int bk = bwk[0][t];
#pragma unroll
        for (int s = 1; s < 8; ++s) {
            const float d = bwd[s][t]; const int k = bwk[s][t];
            if (d < bb || (d == bb && k < bk)) { bb = d; bk = k; }
        }
        fk[t] = bk;
        atomicAdd(reinterpret_cast<unsigned int*>(ws) + WS_CNT + bk, 1u);
    }
    __syncthreads();

    // ---- fused epilogue: thread (w,l): row l, channels [8w, 8w+8) ----
    const int bk = fk[l];
    const float4* eq = reinterpret_cast<const float4*>(emb + bk * DIM + w * 8);
    float* outp = out + b * (DIM * HW) + hw0;
    float lsum = 0.f;
#pragma unroll
    for (int i = 0; i < 2; ++i) {
        const float4 q = eq[i];
        const int c0 = w * 8 + 4 * i;
        const float4 xq = *(const float4*)(xs + l * XSTR + c0);  // aligned
        const float d0 = q.x - xq.x, d1 = q.y - xq.y;
        const float d2 = q.z - xq.z, d3 = q.w - xq.w;
        lsum += d0 * d0 + d1 * d1 + d2 * d2 + d3 * d3;
        outp[(c0 + 0) * HW + l] = xq.x + d0;   // STE: x + (q - x)
        outp[(c0 + 1) * HW + l] = xq.y + d1;
        outp[(c0 + 2) * HW + l] = xq.z + d2;
        outp[(c0 + 3) * HW + l] = xq.w + d3;
    }

#pragma unroll
    for (int off = 32; off; off >>= 1) lsum += __shfl_down(lsum, off, 64);
    if (l == 0) lred[w] = lsum;
    __syncthreads();
    if (t == 0) {
        float s = 0.f;
#pragma unroll
        for (int i = 0; i < 8; ++i) s += lred[i];
        atomicAdd(ws + WS_LOSS, s);
    }
}

__global__ void vq_final(float* __restrict__ out, const float* __restrict__ ws) {
    __shared__ float red[16];
    const int t = threadIdx.x;  // 1024 threads
    const unsigned int* counts = reinterpret_cast<const unsigned int*>(ws) + WS_CNT;
    float p = (float)counts[t] * (1.0f / 65536.f);
    float v = p * logf(p + 1e-10f);
#pragma unroll
    for (int off = 32; off; off >>= 1) v += __shfl_down(v, off, 64);
    if ((t & 63) == 0) red[t >> 6] = v;
    __syncthreads();
    if (t == 0) {
        float s = 0.f;
#pragma unroll
        for (int i = 0; i < 16; ++i) s += red[i];
        out[OUT_ELEMS]     = 0.25f * (1.0f / (float)OUT_ELEMS) * ws[WS_LOSS];
        out[OUT_ELEMS + 1] = expf(-s);
    }
}

extern "C" void kernel_launch(void* const* d_in, const int* in_sizes, int n_in,
                              void* d_out, int out_size, void* d_ws, size_t ws_size,
                              hipStream_t stream) {
    const float* in  = (const float*)d_in[0];
    const float* emb = (const float*)d_in[1];
    float* out = (float*)d_out;
    float* ws  = (float*)d_ws;

    vq_init<<<4, 256, 0, stream>>>(emb, ws);
    vq_main<<<N_ROWS / 64, 512, 0, stream>>>(in, emb, out, ws);
    vq_final<<<1, 1024, 0, stream>>>(out, ws);
}

// Round 10
// 385.930 us; speedup vs baseline: 1.0043x; 1.0043x over previous
//
#include <hip/hip_runtime.h>
#include <stdint.h>

// VectorQuantizer (eval fwd): inputs [64,64,32,32] f32 NCHW, embedding [1024,64] f32.
// Outputs concatenated: quantized [64,64,32,32] f32, loss scalar, perplexity scalar.
//
// Round-10 = round-9 occupancy (8 waves/SIMD) x round-8 codegen (acc[8], VGPR 44).
//  Round 9's acc[16] overflowed the 64-VGPR cap of __launch_bounds__(512,8) ->
//  acc spilled to scratch (VGPR_Count=32, FETCH 144MB, WRITE 161MB, 423us).
//  Reverting to the r8 inner loop (acc[8]+xc[8], 16 code-groups of 8 per wave)
//  keeps the live set ~30 VGPRs -> no spill at the 64-reg cap.
//  - 512-thread blocks: 8 waves, k-split 8 x 128 codes, 64 rows/block,
//    grid 1024 -> 4 blocks/CU -> 8 waves/SIMD.
//  - e/e2 via readfirstlane-uniform addresses -> s_load scalar pipe (r8-proven).
// Distance arithmetic unchanged: dist = ||e||^2 - 2 x.e (bit-exact selections,
// absmax 0.0 in rounds 2/3/5/6/7/8/9).

#define K_CODES 1024
#define DIM 64
#define HW 1024          // 32*32
#define N_ROWS 65536
#define OUT_ELEMS 4194304
#define XSTR 68          // x row stride in dwords

// ws layout (float indices)
#define WS_E2   0        // 1024 f32: ||e_k||^2
#define WS_CNT  1024     // 1024 u32: counts
#define WS_LOSS 2048     // 1 f32

__global__ void vq_init(const float* __restrict__ emb, float* __restrict__ ws) {
    const int k = blockIdx.x * blockDim.x + threadIdx.x;  // 1024 threads total
    if (k < K_CODES) {
        const float4* e4 = reinterpret_cast<const float4*>(emb + k * DIM);
        float s = 0.f;
#pragma unroll
        for (int i = 0; i < DIM / 4; ++i) {
            float4 v = e4[i];
            s += v.x * v.x + v.y * v.y + v.z * v.z + v.w * v.w;
        }
        ws[WS_E2 + k] = s;
        reinterpret_cast<unsigned int*>(ws)[WS_CNT + k] = 0u;
    }
    if (blockIdx.x == 0 && threadIdx.x == 0) ws[WS_LOSS] = 0.f;
}

__global__ __launch_bounds__(512, 8) void vq_main(
    const float* __restrict__ in, const float* __restrict__ emb,
    float* __restrict__ out, float* __restrict__ ws)
{
    __shared__ __align__(16) float xs[64 * XSTR];   // 17408 B
    __shared__ float bwd[8][64];
    __shared__ int   bwk[8][64];
    __shared__ int   fk[64];
    __shared__ float lred[8];

    const int t = threadIdx.x;
    const int w = t >> 6;        // wave id 0..7
    const int l = t & 63;        // pixel-row within block
    const int w_u = __builtin_amdgcn_readfirstlane(w);   // SGPR wave id

    const int row0 = blockIdx.x * 64;
    const int b = row0 >> 10, hw0 = row0 & 1023;
    const float* xin = in + b * (DIM * HW) + hw0;

    // ---- stage x tile: thread (w,l) loads channels [8w, 8w+8) of row l ----
#pragma unroll
    for (int cc = 0; cc < 8; ++cc) {
        const int c = w * 8 + cc;
        xs[l * XSTR + c] = xin[c * HW + l];   // lanes l consecutive -> coalesced
    }
    __syncthreads();

    // ---- argmin over this wave's 128 codes (k0 wave-uniform) ----
    const float* e2 = ws + WS_E2;
    const float* xrow = xs + l * XSTR;
    float best = 3.4e38f;
    int   bestk = 0;
    const int k0 = w_u * 128;

    for (int kg = 0; kg < 128; kg += 8) {
        float acc[8] = {0.f, 0.f, 0.f, 0.f, 0.f, 0.f, 0.f, 0.f};
#pragma unroll
        for (int ch = 0; ch < 8; ++ch) {
            float xc[8];
            *(float4*)(xc)     = *(const float4*)(xrow + ch * 8);      // ds_read_b128
            *(float4*)(xc + 4) = *(const float4*)(xrow + ch * 8 + 4);  // ds_read_b128
#pragma unroll
            for (int c = 0; c < 8; ++c) {
                const float* e = emb + (k0 + kg + c) * DIM + ch * 8;   // uniform -> s_load
#pragma unroll
                for (int j = 0; j < 8; ++j)
                    acc[c] = fmaf(e[j], xc[j], acc[c]);
            }
        }
#pragma unroll
        for (int c = 0; c < 8; ++c) {
            const int k = k0 + kg + c;
            const float dist = fmaf(-2.f, acc[c], e2[k]);
            if (dist < best) { best = dist; bestk = k; }   // strict < : first occurrence
        }
    }

    bwd[w][l] = best;
    bwk[w][l] = bestk;
    __syncthreads();

    // ---- lex-merge across the 8 waves (k-ranges ascending) ----
    if (t < 64) {
        float bb = bwd[0][t]; int bk = bwk[0][t];
#pragma unroll
        for (int s = 1; s < 8; ++s) {
            const float d = bwd[s][t]; const int k = bwk[s][t];
            if (d < bb || (d == bb && k < bk)) { bb = d; bk = k; }
        }
        fk[t] = bk;
        atomicAdd(reinterpret_cast<unsigned int*>(ws) + WS_CNT + bk, 1u);
    }
    __syncthreads();

    // ---- fused epilogue: thread (w,l): row l, channels [8w, 8w+8) ----
    const int bk = fk[l];
    const float4* eq = reinterpret_cast<const float4*>(emb + bk * DIM + w * 8);
    float* outp = out + b * (DIM * HW) + hw0;
    float lsum = 0.f;
#pragma unroll
    for (int i = 0; i < 2; ++i) {
        const float4 q = eq[i];
        const int c0 = w * 8 + 4 * i;
        const float4 xq = *(const float4*)(xs + l * XSTR + c0);  // aligned
        const float d0 = q.x - xq.x, d1 = q.y - xq.y;
        const float d2 = q.z - xq.z, d3 = q.w - xq.w;
        lsum += d0 * d0 + d1 * d1 + d2 * d2 + d3 * d3;
        outp[(c0 + 0) * HW + l] = xq.x + d0;   // STE: x + (q - x)
        outp[(c0 + 1) * HW + l] = xq.y + d1;
        outp[(c0 + 2) * HW + l] = xq.z + d2;
        outp[(c0 + 3) * HW + l] = xq.w + d3;
    }

#pragma unroll
    for (int off = 32; off; off >>= 1) lsum += __shfl_down(lsum, off, 64);
    if (l == 0) lred[w] = lsum;
    __syncthreads();
    if (t == 0) {
        float s = 0.f;
#pragma unroll
        for (int i = 0; i < 8; ++i) s += lred[i];
        atomicAdd(ws + WS_LOSS, s);
    }
}

__global__ void vq_final(float* __restrict__ out, const float* __restrict__ ws) {
    __shared__ float red[16];
    const int t = threadIdx.x;  // 1024 threads
    const unsigned int* counts = reinterpret_cast<const unsigned int*>(ws) + WS_CNT;
    float p = (float)counts[t] * (1.0f / 65536.f);
    float v = p * logf(p + 1e-10f);
#pragma unroll
    for (int off = 32; off; off >>= 1) v += __shfl_down(v, off, 64);
    if ((t & 63) == 0) red[t >> 6] = v;
    __syncthreads();
    if (t == 0) {
        float s = 0.f;
#pragma unroll
        for (int i = 0; i < 16; ++i) s += red[i];
        out[OUT_ELEMS]     = 0.25f * (1.0f / (float)OUT_ELEMS) * ws[WS_LOSS];
        out[OUT_ELEMS + 1] = expf(-s);
    }
}

extern "C" void kernel_launch(void* const* d_in, const int* in_sizes, int n_in,
                              void* d_out, int out_size, void* d_ws, size_t ws_size,
                              hipStream_t stream) {
    const float* in  = (const float*)d_in[0];
    const float* emb = (const float*)d_in[1];
    float* out = (float*)d_out;
    float* ws  = (float*)d_ws;

    vq_init<<<4, 256, 0, stream>>>(emb, ws);
    vq_main<<<N_ROWS / 64, 512, 0, stream>>>(in, emb, out, ws);
    vq_final<<<1, 1024, 0, stream>>>(out, ws);
}

// Round 11
// 165.183 us; speedup vs baseline: 2.3464x; 2.3364x over previous
//
#include <hip/hip_runtime.h>
#include <stdint.h>

// VectorQuantizer (eval fwd): inputs [64,64,32,32] f32 NCHW, embedding [1024,64] f32.
// Outputs concatenated: quantized [64,64,32,32] f32, loss scalar, perplexity scalar.
//
// Round-11: identical to round 10 EXCEPT __launch_bounds__(512, 4).
//  Rounds 9/10 proved (512, 8) makes hipcc budget 32 VGPRs/wave (it reads
//  arg2*B as 64 waves/CU = 16 waves/SIMD) -> acc+xc spill to scratch
//  (VGPR_Count=32, ~300 MB scratch traffic, VALUBusy 29%). With (512, 4)
//  the budget is >=64 VGPRs; the r8-proven inner loop needs ~44 -> no spill,
//  and at VGPR~44 hardware still reaches 8 waves/SIMD (r9's TLP, r8's codegen).
//  - 512-thread blocks: 8 waves, k-split 8 x 128 codes, 64 rows/block,
//    grid 1024 -> 4 blocks/CU -> 8 waves/SIMD.
//  - e/e2 via readfirstlane-uniform addresses -> s_load scalar pipe (r8-proven).
// Distance arithmetic unchanged: dist = ||e||^2 - 2 x.e (bit-exact selections,
// absmax 0.0 in rounds 2/3/5/6/7/8/9/10).

#define K_CODES 1024
#define DIM 64
#define HW 1024          // 32*32
#define N_ROWS 65536
#define OUT_ELEMS 4194304
#define XSTR 68          // x row stride in dwords

// ws layout (float indices)
#define WS_E2   0        // 1024 f32: ||e_k||^2
#define WS_CNT  1024     // 1024 u32: counts
#define WS_LOSS 2048     // 1 f32

__global__ void vq_init(const float* __restrict__ emb, float* __restrict__ ws) {
    const int k = blockIdx.x * blockDim.x + threadIdx.x;  // 1024 threads total
    if (k < K_CODES) {
        const float4* e4 = reinterpret_cast<const float4*>(emb + k * DIM);
        float s = 0.f;
#pragma unroll
        for (int i = 0; i < DIM / 4; ++i) {
            float4 v = e4[i];
            s += v.x * v.x + v.y * v.y + v.z * v.z + v.w * v.w;
        }
        ws[WS_E2 + k] = s;
        reinterpret_cast<unsigned int*>(ws)[WS_CNT + k] = 0u;
    }
    if (blockIdx.x == 0 && threadIdx.x == 0) ws[WS_LOSS] = 0.f;
}

__global__ __launch_bounds__(512, 4) void vq_main(
    const float* __restrict__ in, const float* __restrict__ emb,
    float* __restrict__ out, float* __restrict__ ws)
{
    __shared__ __align__(16) float xs[64 * XSTR];   // 17408 B
    __shared__ float bwd[8][64];
    __shared__ int   bwk[8][64];
    __shared__ int   fk[64];
    __shared__ float lred[8];

    const int t = threadIdx.x;
    const int w = t >> 6;        // wave id 0..7
    const int l = t & 63;        // pixel-row within block
    const int w_u = __builtin_amdgcn_readfirstlane(w);   // SGPR wave id

    const int row0 = blockIdx.x * 64;
    const int b = row0 >> 10, hw0 = row0 & 1023;
    const float* xin = in + b * (DIM * HW) + hw0;

    // ---- stage x tile: thread (w,l) loads channels [8w, 8w+8) of row l ----
#pragma unroll
    for (int cc = 0; cc < 8; ++cc) {
        const int c = w * 8 + cc;
        xs[l * XSTR + c] = xin[c * HW + l];   // lanes l consecutive -> coalesced
    }
    __syncthreads();

    // ---- argmin over this wave's 128 codes (k0 wave-uniform) ----
    const float* e2 = ws + WS_E2;
    const float* xrow = xs + l * XSTR;
    float best = 3.4e38f;
    int   bestk = 0;
    const int k0 = w_u * 128;

    for (int kg = 0; kg < 128; kg += 8) {
        float acc[8] = {0.f, 0.f, 0.f, 0.f, 0.f, 0.f, 0.f, 0.f};
#pragma unroll
        for (int ch = 0; ch < 8; ++ch) {
            float xc[8];
            *(float4*)(xc)     = *(const float4*)(xrow + ch * 8);      // ds_read_b128
            *(float4*)(xc + 4) = *(const float4*)(xrow + ch * 8 + 4);  // ds_read_b128
#pragma unroll
            for (int c = 0; c < 8; ++c) {
                const float* e = emb + (k0 + kg + c) * DIM + ch * 8;   // uniform -> s_load
#pragma unroll
                for (int j = 0; j < 8; ++j)
                    acc[c] = fmaf(e[j], xc[j], acc[c]);
            }
        }
#pragma unroll
        for (int c = 0; c < 8; ++c) {
            const int k = k0 + kg + c;
            const float dist = fmaf(-2.f, acc[c], e2[k]);
            if (dist < best) { best = dist; bestk = k; }   // strict < : first occurrence
        }
    }

    bwd[w][l] = best;
    bwk[w][l] = bestk;
    __syncthreads();

    // ---- lex-merge across the 8 waves (k-ranges ascending) ----
    if (t < 64) {
        float bb = bwd[0][t]; int bk = bwk[0][t];
#pragma unroll
        for (int s = 1; s < 8; ++s) {
            const float d = bwd[s][t]; const int k = bwk[s][t];
            if (d < bb || (d == bb && k < bk)) { bb = d; bk = k; }
        }
        fk[t] = bk;
        atomicAdd(reinterpret_cast<unsigned int*>(ws) + WS_CNT + bk, 1u);
    }
    __syncthreads();

    // ---- fused epilogue: thread (w,l): row l, channels [8w, 8w+8) ----
    const int bk = fk[l];
    const float4* eq = reinterpret_cast<const float4*>(emb + bk * DIM + w * 8);
    float* outp = out + b * (DIM * HW) + hw0;
    float lsum = 0.f;
#pragma unroll
    for (int i = 0; i < 2; ++i) {
        const float4 q = eq[i];
        const int c0 = w * 8 + 4 * i;
        const float4 xq = *(const float4*)(xs + l * XSTR + c0);  // aligned
        const float d0 = q.x - xq.x, d1 = q.y - xq.y;
        const float d2 = q.z - xq.z, d3 = q.w - xq.w;
        lsum += d0 * d0 + d1 * d1 + d2 * d2 + d3 * d3;
        outp[(c0 + 0) * HW + l] = xq.x + d0;   // STE: x + (q - x)
        outp[(c0 + 1) * HW + l] = xq.y + d1;
        outp[(c0 + 2) * HW + l] = xq.z + d2;
        outp[(c0 + 3) * HW + l] = xq.w + d3;
    }

#pragma unroll
    for (int off = 32; off; off >>= 1) lsum += __shfl_down(lsum, off, 64);
    if (l == 0) lred[w] = lsum;
    __syncthreads();
    if (t == 0) {
        float s = 0.f;
#pragma unroll
        for (int i = 0; i < 8; ++i) s += lred[i];
        atomicAdd(ws + WS_LOSS, s);
    }
}

__global__ void vq_final(float* __restrict__ out, const float* __restrict__ ws) {
    __shared__ float red[16];
    const int t = threadIdx.x;  // 1024 threads
    const unsigned int* counts = reinterpret_cast<const unsigned int*>(ws) + WS_CNT;
    float p = (float)counts[t] * (1.0f / 65536.f);
    float v = p * logf(p + 1e-10f);
#pragma unroll
    for (int off = 32; off; off >>= 1) v += __shfl_down(v, off, 64);
    if ((t & 63) == 0) red[t >> 6] = v;
    __syncthreads();
    if (t == 0) {
        float s = 0.f;
#pragma unroll
        for (int i = 0; i < 16; ++i) s += red[i];
        out[OUT_ELEMS]     = 0.25f * (1.0f / (float)OUT_ELEMS) * ws[WS_LOSS];
        out[OUT_ELEMS + 1] = expf(-s);
    }
}

extern "C" void kernel_launch(void* const* d_in, const int* in_sizes, int n_in,
                              void* d_out, int out_size, void* d_ws, size_t ws_size,
                              hipStream_t stream) {
    const float* in  = (const float*)d_in[0];
    const float* emb = (const float*)d_in[1];
    float* out = (float*)d_out;
    float* ws  = (float*)d_ws;

    vq_init<<<4, 256, 0, stream>>>(emb, ws);
    vq_main<<<N_ROWS / 64, 512, 0, stream>>>(in, emb, out, ws);
    vq_final<<<1, 1024, 0, stream>>>(out, ws);
}

// Round 12
// 143.845 us; speedup vs baseline: 2.6945x; 1.1483x over previous
//
#include <hip/hip_runtime.h>
#include <stdint.h>

// VectorQuantizer (eval fwd): inputs [64,64,32,32] f32 NCHW, embedding [1024,64] f32.
// Outputs concatenated: quantized [64,64,32,32] f32, loss scalar, perplexity scalar.
//
// Round-12 = round-11 structure + v_pk_fma_f32 inner loop.
//  r11 counters: VGPR 44 (no spill), VALUBusy 73%, busy-time ~131us vs 54.6us
//  scalar-FMA floor. CDNA4's packed fp32 FMA (v_pk_fma_f32, 2 FMA/instr -- the
//  157 TF spec rate) halves the FMA instruction stream: floor 27.3us.
//  e rides as the single SGPR operand (VOP3P allows 1 sgpr src); x pairs from
//  the LDS tile. acc = float2 per code: live set ~44 VGPRs, same as r11.
//  - 512-thread blocks: 8 waves, k-split 8 x 128 codes, 64 rows/block,
//    grid 1024 -> 4 blocks/CU -> 8 waves/SIMD; __launch_bounds__(512,4)
//    (the (512,8) variant budgets 32 VGPRs on this toolchain -> spills).
//  - e/e2 via readfirstlane-uniform addresses -> s_load scalar pipe.
// dist = ||e||^2 - 2 x.e; summation order now 2 chains/code (was 4) --
// argmin robust to ~1e-5 rounding (absmax 0.0 across r2-r11 vs jnp's own order).

#define K_CODES 1024
#define DIM 64
#define HW 1024          // 32*32
#define N_ROWS 65536
#define OUT_ELEMS 4194304
#define XSTR 68          // x row stride in dwords

// ws layout (float indices)
#define WS_E2   0        // 1024 f32: ||e_k||^2
#define WS_CNT  1024     // 1024 u32: counts
#define WS_LOSS 2048     // 1 f32

__global__ void vq_init(const float* __restrict__ emb, float* __restrict__ ws) {
    const int k = blockIdx.x * blockDim.x + threadIdx.x;  // 1024 threads total
    if (k < K_CODES) {
        const float4* e4 = reinterpret_cast<const float4*>(emb + k * DIM);
        float s = 0.f;
#pragma unroll
        for (int i = 0; i < DIM / 4; ++i) {
            float4 v = e4[i];
            s += v.x * v.x + v.y * v.y + v.z * v.z + v.w * v.w;
        }
        ws[WS_E2 + k] = s;
        reinterpret_cast<unsigned int*>(ws)[WS_CNT + k] = 0u;
    }
    if (blockIdx.x == 0 && threadIdx.x == 0) ws[WS_LOSS] = 0.f;
}

__global__ __launch_bounds__(512, 4) void vq_main(
    const float* __restrict__ in, const float* __restrict__ emb,
    float* __restrict__ out, float* __restrict__ ws)
{
    __shared__ __align__(16) float xs[64 * XSTR];   // 17408 B
    __shared__ float bwd[8][64];
    __shared__ int   bwk[8][64];
    __shared__ int   fk[64];
    __shared__ float lred[8];

    const int t = threadIdx.x;
    const int w = t >> 6;        // wave id 0..7
    const int l = t & 63;        // pixel-row within block
    const int w_u = __builtin_amdgcn_readfirstlane(w);   // SGPR wave id

    const int row0 = blockIdx.x * 64;
    const int b = row0 >> 10, hw0 = row0 & 1023;
    const float* xin = in + b * (DIM * HW) + hw0;

    // ---- stage x tile: thread (w,l) loads channels [8w, 8w+8) of row l ----
#pragma unroll
    for (int cc = 0; cc < 8; ++cc) {
        const int c = w * 8 + cc;
        xs[l * XSTR + c] = xin[c * HW + l];   // lanes l consecutive -> coalesced
    }
    __syncthreads();

    // ---- argmin over this wave's 128 codes (k0 wave-uniform) ----
    const float* e2 = ws + WS_E2;
    const float* xrow = xs + l * XSTR;
    float best = 3.4e38f;
    int   bestk = 0;
    const int k0 = w_u * 128;

    for (int kg = 0; kg < 128; kg += 8) {
        float2 acc[8];
#pragma unroll
        for (int c = 0; c < 8; ++c) acc[c] = make_float2(0.f, 0.f);
#pragma unroll
        for (int ch = 0; ch < 8; ++ch) {
            float2 xc[4];
            *(float4*)(&xc[0]) = *(const float4*)(xrow + ch * 8);      // ds_read_b128
            *(float4*)(&xc[2]) = *(const float4*)(xrow + ch * 8 + 4);  // ds_read_b128
#pragma unroll
            for (int c = 0; c < 8; ++c) {
                // uniform address -> s_load; "s" constraint keeps e in SGPRs
                const float2* ep = (const float2*)(emb + (k0 + kg + c) * DIM + ch * 8);
#pragma unroll
                for (int p = 0; p < 4; ++p) {
                    const float2 ev = ep[p];
                    // packed: acc.lo += ev.lo*xc.lo ; acc.hi += ev.hi*xc.hi
                    asm volatile("v_pk_fma_f32 %0, %1, %2, %0"
                                 : "+v"(acc[c])
                                 : "s"(ev), "v"(xc[p]));
                }
            }
        }
#pragma unroll
        for (int c = 0; c < 8; ++c) {
            const int k = k0 + kg + c;
            const float dot  = acc[c].x + acc[c].y;
            const float dist = fmaf(-2.f, dot, e2[k]);
            if (dist < best) { best = dist; bestk = k; }   // strict < : first occurrence
        }
    }

    bwd[w][l] = best;
    bwk[w][l] = bestk;
    __syncthreads();

    // ---- lex-merge across the 8 waves (k-ranges ascending) ----
    if (t < 64) {
        float bb = bwd[0][t]; int bk = bwk[0][t];
#pragma unroll
        for (int s = 1; s < 8; ++s) {
            const float d = bwd[s][t]; const int k = bwk[s][t];
            if (d < bb || (d == bb && k < bk)) { bb = d; bk = k; }
        }
        fk[t] = bk;
        atomicAdd(reinterpret_cast<unsigned int*>(ws) + WS_CNT + bk, 1u);
    }
    __syncthreads();

    // ---- fused epilogue: thread (w,l): row l, channels [8w, 8w+8) ----
    const int bk = fk[l];
    const float4* eq = reinterpret_cast<const float4*>(emb + bk * DIM + w * 8);
    float* outp = out + b * (DIM * HW) + hw0;
    float lsum = 0.f;
#pragma unroll
    for (int i = 0; i < 2; ++i) {
        const float4 q = eq[i];
        const int c0 = w * 8 + 4 * i;
        const float4 xq = *(const float4*)(xs + l * XSTR + c0);  // aligned
        const float d0 = q.x - xq.x, d1 = q.y - xq.y;
        const float d2 = q.z - xq.z, d3 = q.w - xq.w;
        lsum += d0 * d0 + d1 * d1 + d2 * d2 + d3 * d3;
        outp[(c0 + 0) * HW + l] = xq.x + d0;   // STE: x + (q - x)
        outp[(c0 + 1) * HW + l] = xq.y + d1;
        outp[(c0 + 2) * HW + l] = xq.z + d2;
        outp[(c0 + 3) * HW + l] = xq.w + d3;
    }

#pragma unroll
    for (int off = 32; off; off >>= 1) lsum += __shfl_down(lsum, off, 64);
    if (l == 0) lred[w] = lsum;
    __syncthreads();
    if (t == 0) {
        float s = 0.f;
#pragma unroll
        for (int i = 0; i < 8; ++i) s += lred[i];
        atomicAdd(ws + WS_LOSS, s);
    }
}

__global__ void vq_final(float* __restrict__ out, const float* __restrict__ ws) {
    __shared__ float red[16];
    const int t = threadIdx.x;  // 1024 threads
    const unsigned int* counts = reinterpret_cast<const unsigned int*>(ws) + WS_CNT;
    float p = (float)counts[t] * (1.0f / 65536.f);
    float v = p * logf(p + 1e-10f);
#pragma unroll
    for (int off = 32; off; off >>= 1) v += __shfl_down(v, off, 64);
    if ((t & 63) == 0) red[t >> 6] = v;
    __syncthreads();
    if (t == 0) {
        float s = 0.f;
#pragma unroll
        for (int i = 0; i < 16; ++i) s += red[i];
        out[OUT_ELEMS]     = 0.25f * (1.0f / (float)OUT_ELEMS) * ws[WS_LOSS];
        out[OUT_ELEMS + 1] = expf(-s);
    }
}

extern "C" void kernel_launch(void* const* d_in, const int* in_sizes, int n_in,
                              void* d_out, int out_size, void* d_ws, size_t ws_size,
                              hipStream_t stream) {
    const float* in  = (const float*)d_in[0];
    const float* emb = (const float*)d_in[1];
    float* out = (float*)d_out;
    float* ws  = (float*)d_ws;

    vq_init<<<4, 256, 0, stream>>>(emb, ws);
    vq_main<<<N_ROWS / 64, 512, 0, stream>>>(in, emb, out, ws);
    vq_final<<<1, 1024, 0, stream>>>(out, ws);
}

// Round 13
// 133.365 us; speedup vs baseline: 2.9063x; 1.0786x over previous
//
#include <hip/hip_runtime.h>
#include <stdint.h>

// VectorQuantizer (eval fwd): inputs [64,64,32,32] f32 NCHW, embedding [1024,64] f32.
// Outputs concatenated: quantized [64,64,32,32] f32, loss scalar, perplexity scalar.
//
// Round-13 = round-12 pk_fma math + restored scalar-feed batching.
//  r12's asm VOLATILE with per-float2 "s" operands killed e-prefetch batching
//  (SGPR 112->32, VALUBusy 73->34.5%): each 8B e pair was s_loaded just-in-time.
//  Fix: (a) non-volatile asm -> scheduler may pipeline across iterations;
//       (b) e staged through C locals in 64B runs (ev[8] float2) -> compiler
//           merges to s_load_dwordx16: 1 scalar instr per 8 pk_fma.
//  Inner loop: 4 chunks of 16 dims; per (code, chunk): 1 dwordx16 + 8 pk_fma.
//  - 512-thread blocks: 8 waves, k-split 8 x 128 codes, 64 rows/block,
//    grid 1024 -> 4 blocks/CU; __launch_bounds__(512,4) (the (512,8) variant
//    budgets 32 VGPRs on this toolchain -> spills).
//  - e/e2 via readfirstlane-uniform addresses -> s_load scalar pipe.
// dist = ||e||^2 - 2 x.e; 2-chain summation per code (r12-proven, absmax 0.0).

#define K_CODES 1024
#define DIM 64
#define HW 1024          // 32*32
#define N_ROWS 65536
#define OUT_ELEMS 4194304
#define XSTR 68          // x row stride in dwords

// ws layout (float indices)
#define WS_E2   0        // 1024 f32: ||e_k||^2
#define WS_CNT  1024     // 1024 u32: counts
#define WS_LOSS 2048     // 1 f32

__global__ void vq_init(const float* __restrict__ emb, float* __restrict__ ws) {
    const int k = blockIdx.x * blockDim.x + threadIdx.x;  // 1024 threads total
    if (k < K_CODES) {
        const float4* e4 = reinterpret_cast<const float4*>(emb + k * DIM);
        float s = 0.f;
#pragma unroll
        for (int i = 0; i < DIM / 4; ++i) {
            float4 v = e4[i];
            s += v.x * v.x + v.y * v.y + v.z * v.z + v.w * v.w;
        }
        ws[WS_E2 + k] = s;
        reinterpret_cast<unsigned int*>(ws)[WS_CNT + k] = 0u;
    }
    if (blockIdx.x == 0 && threadIdx.x == 0) ws[WS_LOSS] = 0.f;
}

__global__ __launch_bounds__(512, 4) void vq_main(
    const float* __restrict__ in, const float* __restrict__ emb,
    float* __restrict__ out, float* __restrict__ ws)
{
    __shared__ __align__(16) float xs[64 * XSTR];   // 17408 B
    __shared__ float bwd[8][64];
    __shared__ int   bwk[8][64];
    __shared__ int   fk[64];
    __shared__ float lred[8];

    const int t = threadIdx.x;
    const int w = t >> 6;        // wave id 0..7
    const int l = t & 63;        // pixel-row within block
    const int w_u = __builtin_amdgcn_readfirstlane(w);   // SGPR wave id

    const int row0 = blockIdx.x * 64;
    const int b = row0 >> 10, hw0 = row0 & 1023;
    const float* xin = in + b * (DIM * HW) + hw0;

    // ---- stage x tile: thread (w,l) loads channels [8w, 8w+8) of row l ----
#pragma unroll
    for (int cc = 0; cc < 8; ++cc) {
        const int c = w * 8 + cc;
        xs[l * XSTR + c] = xin[c * HW + l];   // lanes l consecutive -> coalesced
    }
    __syncthreads();

    // ---- argmin over this wave's 128 codes (k0 wave-uniform) ----
    const float* e2 = ws + WS_E2;
    const float* xrow = xs + l * XSTR;
    float best = 3.4e38f;
    int   bestk = 0;
    const int k0 = w_u * 128;

    for (int kg = 0; kg < 128; kg += 8) {
        float2 acc[8];
#pragma unroll
        for (int c = 0; c < 8; ++c) acc[c] = make_float2(0.f, 0.f);
#pragma unroll
        for (int ch = 0; ch < 4; ++ch) {        // 4 chunks of 16 dims
            float2 xc[8];
            *(float4*)(&xc[0]) = *(const float4*)(xrow + ch * 16);
            *(float4*)(&xc[2]) = *(const float4*)(xrow + ch * 16 + 4);
            *(float4*)(&xc[4]) = *(const float4*)(xrow + ch * 16 + 8);
            *(float4*)(&xc[6]) = *(const float4*)(xrow + ch * 16 + 12);
#pragma unroll
            for (int c = 0; c < 8; ++c) {
                // 64B run of e -> compiler merges to s_load_dwordx16
                const float2* ep = (const float2*)(emb + (k0 + kg + c) * DIM + ch * 16);
                float2 ev[8];
#pragma unroll
                for (int j = 0; j < 8; ++j) ev[j] = ep[j];
#pragma unroll
                for (int j = 0; j < 8; ++j) {
                    // packed fp32 FMA: acc.lo += e.lo*x.lo ; acc.hi += e.hi*x.hi
                    // non-volatile: scheduler may pipeline/prefetch freely
                    asm("v_pk_fma_f32 %0, %1, %2, %0"
                        : "+v"(acc[c])
                        : "s"(ev[j]), "v"(xc[j]));
                }
            }
        }
#pragma unroll
        for (int c = 0; c < 8; ++c) {
            const int k = k0 + kg + c;
            const float dot  = acc[c].x + acc[c].y;
            const float dist = fmaf(-2.f, dot, e2[k]);
            if (dist < best) { best = dist; bestk = k; }   // strict < : first occurrence
        }
    }

    bwd[w][l] = best;
    bwk[w][l] = bestk;
    __syncthreads();

    // ---- lex-merge across the 8 waves (k-ranges ascending) ----
    if (t < 64) {
        float bb = bwd[0][t]; int bk = bwk[0][t];
#pragma unroll
        for (int s = 1; s < 8; ++s) {
            const float d = bwd[s][t]; const int k = bwk[s][t];
            if (d < bb || (d == bb && k < bk)) { bb = d; bk = k; }
        }
        fk[t] = bk;
        atomicAdd(reinterpret_cast<unsigned int*>(ws) + WS_CNT + bk, 1u);
    }
    __syncthreads();

    // ---- fused epilogue: thread (w,l): row l, channels [8w, 8w+8) ----
    const int bk = fk[l];
    const float4* eq = reinterpret_cast<const float4*>(emb + bk * DIM + w * 8);
    float* outp = out + b * (DIM * HW) + hw0;
    float lsum = 0.f;
#pragma unroll
    for (int i = 0; i < 2; ++i) {
        const float4 q = eq[i];
        const int c0 = w * 8 + 4 * i;
        const float4 xq = *(const float4*)(xs + l * XSTR + c0);  // aligned
        const float d0 = q.x - xq.x, d1 = q.y - xq.y;
        const float d2 = q.z - xq.z, d3 = q.w - xq.w;
        lsum += d0 * d0 + d1 * d1 + d2 * d2 + d3 * d3;
        outp[(c0 + 0) * HW + l] = xq.x + d0;   // STE: x + (q - x)
        outp[(c0 + 1) * HW + l] = xq.y + d1;
        outp[(c0 + 2) * HW + l] = xq.z + d2;
        outp[(c0 + 3) * HW + l] = xq.w + d3;
    }

#pragma unroll
    for (int off = 32; off; off >>= 1) lsum += __shfl_down(lsum, off, 64);
    if (l == 0) lred[w] = lsum;
    __syncthreads();
    if (t == 0) {
        float s = 0.f;
#pragma unroll
        for (int i = 0; i < 8; ++i) s += lred[i];
        atomicAdd(ws + WS_LOSS, s);
    }
}

__global__ void vq_final(float* __restrict__ out, const float* __restrict__ ws) {
    __shared__ float red[16];
    const int t = threadIdx.x;  // 1024 threads
    const unsigned int* counts = reinterpret_cast<const unsigned int*>(ws) + WS_CNT;
    float p = (float)counts[t] * (1.0f / 65536.f);
    float v = p * logf(p + 1e-10f);
#pragma unroll
    for (int off = 32; off; off >>= 1) v += __shfl_down(v, off, 64);
    if ((t & 63) == 0) red[t >> 6] = v;
    __syncthreads();
    if (t == 0) {
        float s = 0.f;
#pragma unroll
        for (int i = 0; i < 16; ++i) s += red[i];
        out[OUT_ELEMS]     = 0.25f * (1.0f / (float)OUT_ELEMS) * ws[WS_LOSS];
        out[OUT_ELEMS + 1] = expf(-s);
    }
}

extern "C" void kernel_launch(void* const* d_in, const int* in_sizes, int n_in,
                              void* d_out, int out_size, void* d_ws, size_t ws_size,
                              hipStream_t stream) {
    const float* in  = (const float*)d_in[0];
    const float* emb = (const float*)d_in[1];
    float* out = (float*)d_out;
    float* ws  = (float*)d_ws;

    vq_init<<<4, 256, 0, stream>>>(emb, ws);
    vq_main<<<N_ROWS / 64, 512, 0, stream>>>(in, emb, out, ws);
    vq_final<<<1, 1024, 0, stream>>>(out, ws);
}

// Round 14
// 115.152 us; speedup vs baseline: 3.3659x; 1.1582x over previous
//
#include <hip/hip_runtime.h>
#include <stdint.h>

// VectorQuantizer (eval fwd): inputs [64,64,32,32] f32 NCHW, embedding [1024,64] f32.
// Outputs concatenated: quantized [64,64,32,32] f32, loss scalar, perplexity scalar.
//
// Round-14 = round-13 pk_fma kernel + 2 rows/thread for e-reuse.
//  r13 was scalar-feed-rate-bound: per code one s_load_dwordx16 (~200cyc L2,
//  ~4-5 in flight -> 1 per ~50cyc) fed only 16 cyc of pk -> VALUBusy 48%.
//  Processing 2 rows/thread doubles pk per e-byte (32 cyc/code) and halves
//  total waves; each wave now compute-dominated.
//  - 512-thread blocks, 128 rows/block (thread owns rows l and l+64),
//    8 waves x 128 codes, grid 512 -> 2 blocks/CU -> 4 waves/SIMD.
//  - __launch_bounds__(512,2): VGPR budget 128 -> no spill at ~75 live
//    (r9/r10 lesson: (512,8) budgets 32 and spills; grid caps residency anyway).
//  - e/e2 via readfirstlane-uniform addresses -> s_load scalar pipe; ev staged
//    in 64B runs -> s_load_dwordx16 (r13-proven).
// dist = ||e||^2 - 2 x.e; 2-chain pk summation per code (r13-proven, absmax 0.0).

#define K_CODES 1024
#define DIM 64
#define HW 1024          // 32*32
#define N_ROWS 65536
#define OUT_ELEMS 4194304
#define XSTR 68          // x row stride in dwords
#define RPB 128          // rows per block

// ws layout (float indices)
#define WS_E2   0        // 1024 f32: ||e_k||^2
#define WS_CNT  1024     // 1024 u32: counts
#define WS_LOSS 2048     // 1 f32

__global__ void vq_init(const float* __restrict__ emb, float* __restrict__ ws) {
    const int k = blockIdx.x * blockDim.x + threadIdx.x;  // 1024 threads total
    if (k < K_CODES) {
        const float4* e4 = reinterpret_cast<const float4*>(emb + k * DIM);
        float s = 0.f;
#pragma unroll
        for (int i = 0; i < DIM / 4; ++i) {
            float4 v = e4[i];
            s += v.x * v.x + v.y * v.y + v.z * v.z + v.w * v.w;
        }
        ws[WS_E2 + k] = s;
        reinterpret_cast<unsigned int*>(ws)[WS_CNT + k] = 0u;
    }
    if (blockIdx.x == 0 && threadIdx.x == 0) ws[WS_LOSS] = 0.f;
}

__global__ __launch_bounds__(512, 2) void vq_main(
    const float* __restrict__ in, const float* __restrict__ emb,
    float* __restrict__ out, float* __restrict__ ws)
{
    __shared__ __align__(16) float xs[RPB * XSTR];   // 34816 B
    __shared__ float bwd[8][RPB];
    __shared__ int   bwk[8][RPB];
    __shared__ int   fk[RPB];
    __shared__ float lred[8];

    const int t = threadIdx.x;
    const int w = t >> 6;        // wave id 0..7
    const int l = t & 63;
    const int w_u = __builtin_amdgcn_readfirstlane(w);   // SGPR wave id

    const int row0 = blockIdx.x * RPB;
    const int b = row0 >> 10, hw0 = row0 & 1023;   // 128 | 1024 -> rows stay in one b
    const float* xin = in + b * (DIM * HW) + hw0;

    // ---- stage x tile: thread (w,l): rows l and l+64, channels [8w, 8w+8) ----
#pragma unroll
    for (int rr = 0; rr < 2; ++rr) {
        const int r = rr * 64 + l;
#pragma unroll
        for (int cc = 0; cc < 8; ++cc) {
            const int c = w * 8 + cc;
            xs[r * XSTR + c] = xin[c * HW + r];   // lanes l consecutive -> coalesced
        }
    }
    __syncthreads();

    // ---- argmin over this wave's 128 codes for BOTH rows (k0 wave-uniform) ----
    const float* e2 = ws + WS_E2;
    const float* x0 = xs + l * XSTR;
    const float* x1 = xs + (l + 64) * XSTR;
    float best0 = 3.4e38f, best1 = 3.4e38f;
    int   bk0 = 0, bk1 = 0;
    const int k0 = w_u * 128;

    for (int kg = 0; kg < 128; kg += 8) {
        float2 acc0[8], acc1[8];
#pragma unroll
        for (int c = 0; c < 8; ++c) {
            acc0[c] = make_float2(0.f, 0.f);
            acc1[c] = make_float2(0.f, 0.f);
        }
#pragma unroll
        for (int ch = 0; ch < 4; ++ch) {        // 4 chunks of 16 dims
            float2 xa[8], xb[8];
            *(float4*)(&xa[0]) = *(const float4*)(x0 + ch * 16);
            *(float4*)(&xa[2]) = *(const float4*)(x0 + ch * 16 + 4);
            *(float4*)(&xa[4]) = *(const float4*)(x0 + ch * 16 + 8);
            *(float4*)(&xa[6]) = *(const float4*)(x0 + ch * 16 + 12);
            *(float4*)(&xb[0]) = *(const float4*)(x1 + ch * 16);
            *(float4*)(&xb[2]) = *(const float4*)(x1 + ch * 16 + 4);
            *(float4*)(&xb[4]) = *(const float4*)(x1 + ch * 16 + 8);
            *(float4*)(&xb[6]) = *(const float4*)(x1 + ch * 16 + 12);
#pragma unroll
            for (int c = 0; c < 8; ++c) {
                // 64B run of e -> s_load_dwordx16; feeds 16 pk (2 rows)
                const float2* ep = (const float2*)(emb + (k0 + kg + c) * DIM + ch * 16);
                float2 ev[8];
#pragma unroll
                for (int j = 0; j < 8; ++j) ev[j] = ep[j];
#pragma unroll
                for (int j = 0; j < 8; ++j) {
                    asm("v_pk_fma_f32 %0, %1, %2, %0"
                        : "+v"(acc0[c]) : "s"(ev[j]), "v"(xa[j]));
                    asm("v_pk_fma_f32 %0, %1, %2, %0"
                        : "+v"(acc1[c]) : "s"(ev[j]), "v"(xb[j]));
                }
            }
        }
#pragma unroll
        for (int c = 0; c < 8; ++c) {
            const int k = k0 + kg + c;
            const float e2v = e2[k];
            const float d0 = fmaf(-2.f, acc0[c].x + acc0[c].y, e2v);
            const float d1 = fmaf(-2.f, acc1[c].x + acc1[c].y, e2v);
            if (d0 < best0) { best0 = d0; bk0 = k; }   // strict < : first occurrence
            if (d1 < best1) { best1 = d1; bk1 = k; }
        }
    }

    bwd[w][l]      = best0;  bwk[w][l]      = bk0;
    bwd[w][l + 64] = best1;  bwk[w][l + 64] = bk1;
    __syncthreads();

    // ---- lex-merge across the 8 waves (k-ranges ascending) ----
    if (t < RPB) {
        float bb = bwd[0][t]; int bk = bwk[0][t];
#pragma unroll
        for (int s = 1; s < 8; ++s) {
            const float d = bwd[s][t]; const int k = bwk[s][t];
            if (d < bb || (d == bb && k < bk)) { bb = d; bk = k; }
        }
        fk[t] = bk;
        atomicAdd(reinterpret_cast<unsigned int*>(ws) + WS_CNT + bk, 1u);
    }
    __syncthreads();

    // ---- fused epilogue: thread (w,l): rows l, l+64, channels [8w, 8w+8) ----
    float* outp = out + b * (DIM * HW) + hw0;
    float lsum = 0.f;
#pragma unroll
    for (int rr = 0; rr < 2; ++rr) {
        const int r = rr * 64 + l;
        const int bk = fk[r];
        const float4* eq = reinterpret_cast<const float4*>(emb + bk * DIM + w * 8);
        const float* xrow = xs + r * XSTR;
#pragma unroll
        for (int i = 0; i < 2; ++i) {
            const float4 q = eq[i];
            const int c0 = w * 8 + 4 * i;
            const float4 xq = *(const float4*)(xrow + c0);  // aligned
            const float d0 = q.x - xq.x, d1 = q.y - xq.y;
            const float d2 = q.z - xq.z, d3 = q.w - xq.w;
            lsum += d0 * d0 + d1 * d1 + d2 * d2 + d3 * d3;
            outp[(c0 + 0) * HW + r] = xq.x + d0;   // STE: x + (q - x)
            outp[(c0 + 1) * HW + r] = xq.y + d1;
            outp[(c0 + 2) * HW + r] = xq.z + d2;
            outp[(c0 + 3) * HW + r] = xq.w + d3;
        }
    }

#pragma unroll
    for (int off = 32; off; off >>= 1) lsum += __shfl_down(lsum, off, 64);
    if (l == 0) lred[w] = lsum;
    __syncthreads();
    if (t == 0) {
        float s = 0.f;
#pragma unroll
        for (int i = 0; i < 8; ++i) s += lred[i];
        atomicAdd(ws + WS_LOSS, s);
    }
}

__global__ void vq_final(float* __restrict__ out, const float* __restrict__ ws) {
    __shared__ float red[16];
    const int t = threadIdx.x;  // 1024 threads
    const unsigned int* counts = reinterpret_cast<const unsigned int*>(ws) + WS_CNT;
    float p = (float)counts[t] * (1.0f / 65536.f);
    float v = p * logf(p + 1e-10f);
#pragma unroll
    for (int off = 32; off; off >>= 1) v += __shfl_down(v, off, 64);
    if ((t & 63) == 0) red[t >> 6] = v;
    __syncthreads();
    if (t == 0) {
        float s = 0.f;
#pragma unroll
        for (int i = 0; i < 16; ++i) s += red[i];
        out[OUT_ELEMS]     = 0.25f * (1.0f / (float)OUT_ELEMS) * ws[WS_LOSS];
        out[OUT_ELEMS + 1] = expf(-s);
    }
}

extern "C" void kernel_launch(void* const* d_in, const int* in_sizes, int n_in,
                              void* d_out, int out_size, void* d_ws, size_t ws_size,
                              hipStream_t stream) {
    const float* in  = (const float*)d_in[0];
    const float* emb = (const float*)d_in[1];
    float* out = (float*)d_out;
    float* ws  = (float*)d_ws;

    vq_init<<<4, 256, 0, stream>>>(emb, ws);
    vq_main<<<N_ROWS / RPB, 512, 0, stream>>>(in, emb, out, ws);
    vq_final<<<1, 1024, 0, stream>>>(out, ws);
}